// Round 11
// baseline (112.347 us; speedup 1.0000x reference)
//
#include <hip/hip_runtime.h>

#define NB 128
#define NS 8192
#define NC 64
#define NL (NS / NC)          // 128 steps per chunk
#define M4 (NL / 4)           // 32 float4 groups

#define LOG2E 1.4426950408889634f
#define HLOG2PI 0.918938533204672742f
#define LN2 0.69314718055994531f

// phase23 LDS layout (round-6/8/9-proven)
#define ROWS 20          // padded leading dim
#define UNIT 640         // dual unit: R[16x20] + T[16x20]
#define SLOT 320

__device__ __forceinline__ float fexp2(float x) { return __builtin_amdgcn_exp2f(x); }
__device__ __forceinline__ float flog2(float x) { return __builtin_amdgcn_logf(x); }

__device__ __forceinline__ float gsum16(float v) {
    v += __shfl_xor(v, 1, 16);
    v += __shfl_xor(v, 2, 16);
    v += __shfl_xor(v, 4, 16);
    v += __shfl_xor(v, 8, 16);
    return v;
}
__device__ __forceinline__ float gmax16(float v) {
    v = fmaxf(v, __shfl_xor(v, 1, 16));
    v = fmaxf(v, __shfl_xor(v, 2, 16));
    v = fmaxf(v, __shfl_xor(v, 4, 16));
    v = fmaxf(v, __shfl_xor(v, 8, 16));
    return v;
}

// DPP row-rotate within 16-lane rows. bound_ctrl=TRUE: row_ror is a permutation
// within the row (every source lane valid when exec is full for the row), so
// semantics are unchanged but the compiler drops the old-value tie/mov that
// bound_ctrl=false forces on each rotation.
template <int K>
__device__ __forceinline__ int rotk(int x) {
    return __builtin_amdgcn_mov_dpp(x, 0x120 + K, 0xF, 0xF, true);
}

// One HMM step in rotated-W layout: SCALAR rotate-and-consume (round-8's exact
// arithmetic — no v2f, so no VOP3P operand-pair packing movs). Takes current
// colsum T, returns the new colsum. Renorm lives outside (round-9 skeleton).
__device__ __forceinline__ float step2(float (&W)[16], float T, float xx,
                                       float A2, float B2, float C2) {
    const float amb = 0.9f - 0.1f / 15.0f;
    const float bco = 0.1f / 15.0f;
    float myl = fexp2(fmaf(xx, fmaf(xx, A2, B2), C2));   // ONE exp per lane
    int mi = __float_as_int(myl);
    float bT = bco * T;
    W[0]  = fmaf(amb, W[0],  bT) * myl;
    W[1]  = fmaf(amb, W[1],  bT) * __int_as_float(rotk<1>(mi));
    W[2]  = fmaf(amb, W[2],  bT) * __int_as_float(rotk<2>(mi));
    W[3]  = fmaf(amb, W[3],  bT) * __int_as_float(rotk<3>(mi));
    W[4]  = fmaf(amb, W[4],  bT) * __int_as_float(rotk<4>(mi));
    W[5]  = fmaf(amb, W[5],  bT) * __int_as_float(rotk<5>(mi));
    W[6]  = fmaf(amb, W[6],  bT) * __int_as_float(rotk<6>(mi));
    W[7]  = fmaf(amb, W[7],  bT) * __int_as_float(rotk<7>(mi));
    W[8]  = fmaf(amb, W[8],  bT) * __int_as_float(rotk<8>(mi));
    W[9]  = fmaf(amb, W[9],  bT) * __int_as_float(rotk<9>(mi));
    W[10] = fmaf(amb, W[10], bT) * __int_as_float(rotk<10>(mi));
    W[11] = fmaf(amb, W[11], bT) * __int_as_float(rotk<11>(mi));
    W[12] = fmaf(amb, W[12], bT) * __int_as_float(rotk<12>(mi));
    W[13] = fmaf(amb, W[13], bT) * __int_as_float(rotk<13>(mi));
    W[14] = fmaf(amb, W[14], bT) * __int_as_float(rotk<14>(mi));
    W[15] = fmaf(amb, W[15], bT) * __int_as_float(rotk<15>(mi));
    float s0 = (W[0] + W[1]) + (W[2] + W[3]);
    float s1 = (W[4] + W[5]) + (W[6] + W[7]);
    float s2 = (W[8] + W[9]) + (W[10] + W[11]);
    float s3 = (W[12] + W[13]) + (W[14] + W[15]);
    return (s0 + s1) + (s2 + s3);
}

// Phase 1: round-9 skeleton verbatim (nc=64, fp32 store, peeled first group,
// guarded per-4-step exponent renorm, __launch_bounds__(256,2)); only the step
// body's instruction selection changed (scalar + untied DPP). NOTE: nc=128 /
// 64-step chunks are BANNED — all three inf failures (r5/r7/r10) had them;
// un-renormalized short-chunk products underflow through the phase23 tree.
__global__ __launch_bounds__(256, 2) void hmm_phase1(const float* __restrict__ obvs,
                                                     const float* __restrict__ mu,
                                                     const float* __restrict__ log_sigma,
                                                     float* __restrict__ wsW,
                                                     float* __restrict__ wsM,
                                                     float* __restrict__ out) {
    int tid = blockIdx.x * blockDim.x + threadIdx.x;
    if (tid == 0) out[0] = 0.0f;           // phase23 atomicAdds after this dispatch
    int r = tid & 15;
    int g = tid >> 4;                      // g = b*NC + c
    int b = g >> 6;
    int c = g & (NC - 1);

    float ls = log_sigma[r];
    float mk = mu[r];
    float iv = fexp2(-2.0f * LOG2E * ls);
    float A2 = -0.5f * LOG2E * iv;
    float B2 = LOG2E * mk * iv;
    float C2 = LOG2E * (-0.5f * mk * mk * iv - ls - HLOG2PI);

    float W[16];
#pragma unroll
    for (int k = 0; k < 16; ++k) W[k] = (k == 0) ? 1.0f : 0.0f;  // identity, rotated layout
    int ilog = 0;
    float T = 1.0f;

    const float4* ob4 = (const float4*)(obvs + (long)b * NS) + c * M4;
    float4 xv = ob4[0];
    float4 xn = ob4[1];
    // peeled m=0 group: chunk 0 skips t=0 (handled as init vector in phase23)
    if (c) T = step2(W, T, xv.x, A2, B2, C2);
    T = step2(W, T, xv.y, A2, B2, C2);
    T = step2(W, T, xv.z, A2, B2, C2);
    T = step2(W, T, xv.w, A2, B2, C2);
    {
        int te = (__float_as_int(T) >> 23) & 255;
        int ok = (te != 0);
        float s = ok ? __int_as_float((254 - te) << 23) : 1.0f;
        ilog += ok ? (te - 127) : 0;
#pragma unroll
        for (int k = 0; k < 16; ++k) W[k] *= s;
        T *= s;
    }
    xv = xn;
    for (int m = 1; m < M4; ++m) {
        xn = ob4[(m + 1) < M4 ? (m + 1) : m];
        T = step2(W, T, xv.x, A2, B2, C2);
        T = step2(W, T, xv.y, A2, B2, C2);
        T = step2(W, T, xv.z, A2, B2, C2);
        T = step2(W, T, xv.w, A2, B2, C2);
        // guarded branchless exponent renorm (round-8/9-proven)
        int te = (__float_as_int(T) >> 23) & 255;
        int ok = (te != 0);
        float s = ok ? __int_as_float((254 - te) << 23) : 1.0f;
        ilog += ok ? (te - 127) : 0;
#pragma unroll
        for (int k = 0; k < 16; ++k) W[k] *= s;
        T *= s;
        xv = xn;
    }

    int sid[16];
    sid[0] = r;
    sid[1]  = rotk<1>(r);   sid[2]  = rotk<2>(r);   sid[3]  = rotk<3>(r);
    sid[4]  = rotk<4>(r);   sid[5]  = rotk<5>(r);   sid[6]  = rotk<6>(r);
    sid[7]  = rotk<7>(r);   sid[8]  = rotk<8>(r);   sid[9]  = rotk<9>(r);
    sid[10] = rotk<10>(r);  sid[11] = rotk<11>(r);  sid[12] = rotk<12>(r);
    sid[13] = rotk<13>(r);  sid[14] = rotk<14>(r);  sid[15] = rotk<15>(r);

    float lg = (float)ilog + flog2(T);     // true column log2-sum (T in [1,2))
    float mx = gmax16(lg);                 // chunk max over 16 columns
    float sc = fexp2((float)ilog - mx);    // scale so chunk max colsum = 1
    float* dst = wsW + (long)g * 256 + r;  // M[j][r] at j*16+r (fp32)
#pragma unroll
    for (int k = 0; k < 16; ++k) dst[sid[k] * 16] = W[k] * sc;
    if (r == 0) wsM[g] = mx;
}

// P = Mb * Ma, one product per wave (round-6/8/9-proven).
__device__ __forceinline__ void mat16_mul(float* dR, float* dT,
                                          const float* MbR, const float* MaT,
                                          int lane) {
    int a = lane >> 3;
    int cc = lane & 7;
    float b0[16], b1[16], a0[16], a1[16];
    const float4* pb0 = (const float4*)(MbR + (2 * a) * ROWS);
    const float4* pb1 = (const float4*)(MbR + (2 * a + 1) * ROWS);
    const float4* pa0 = (const float4*)(MaT + (2 * cc) * ROWS);
    const float4* pa1 = (const float4*)(MaT + (2 * cc + 1) * ROWS);
#pragma unroll
    for (int q = 0; q < 4; ++q) {
        *(float4*)&b0[4 * q] = pb0[q];
        *(float4*)&b1[4 * q] = pb1[q];
        *(float4*)&a0[4 * q] = pa0[q];
        *(float4*)&a1[4 * q] = pa1[q];
    }
    float c00 = 0.f, c01 = 0.f, c10 = 0.f, c11 = 0.f;
#pragma unroll
    for (int k = 0; k < 16; ++k) {
        c00 = fmaf(b0[k], a0[k], c00);
        c01 = fmaf(b0[k], a1[k], c01);
        c10 = fmaf(b1[k], a0[k], c10);
        c11 = fmaf(b1[k], a1[k], c11);
    }
    *(float2*)(dR + (2 * a) * ROWS + 2 * cc)     = make_float2(c00, c01);
    *(float2*)(dR + (2 * a + 1) * ROWS + 2 * cc) = make_float2(c10, c11);
    if (dT) {
        *(float2*)(dT + (2 * cc) * ROWS + 2 * a)     = make_float2(c00, c10);
        *(float2*)(dT + (2 * cc + 1) * ROWS + 2 * a) = make_float2(c01, c11);
    }
}

// Phase 2+3: VERBATIM round-8/9-passed kernel.
__global__ __launch_bounds__(256, 2) void hmm_phase23(const float* __restrict__ obvs,
                                                      const float* __restrict__ mu,
                                                      const float* __restrict__ log_sigma,
                                                      const float* __restrict__ prior_logits,
                                                      const float* __restrict__ wsW,
                                                      const float* __restrict__ wsM,
                                                      float* __restrict__ out) {
    __shared__ float smem[12800];   // 51,200 B: stage(8x640) + scr(8x640) + resB(8x320)
    float* stage = smem;
    float* scr   = smem + 5120;
    float* resB  = smem + 10240;

    int bb = blockIdx.x;
    int tid = threadIdx.x;
    int wid = tid >> 6;
    int lane = tid & 63;

    for (int rd = 0; rd < 8; ++rd) {
        const float4* src = (const float4*)(wsW + ((long)bb * NC + rd * 8) * 256);
        __syncthreads();                   // stage reuse vs previous round's reads
#pragma unroll
        for (int q = 0; q < 2; ++q) {
            int f = tid + q * 256;
            float4 v = src[f];
            int m = f >> 6, idx = f & 63, j = idx >> 2, kq = idx & 3;
            *(float4*)(stage + m * UNIT + j * ROWS + kq * 4) = v;
            float* Tb = stage + m * UNIT + SLOT;
            Tb[(4 * kq + 0) * ROWS + j] = v.x;
            Tb[(4 * kq + 1) * ROWS + j] = v.y;
            Tb[(4 * kq + 2) * ROWS + j] = v.z;
            Tb[(4 * kq + 3) * ROWS + j] = v.w;
        }
        __syncthreads();
        // in-round tree 8 -> 4 -> 2 -> 1  (later * earlier)
        if (wid < 4)
            mat16_mul(scr + wid * UNIT, scr + wid * UNIT + SLOT,
                      stage + (2 * wid + 1) * UNIT, stage + (2 * wid) * UNIT + SLOT, lane);
        __syncthreads();
        if (wid < 2)
            mat16_mul(scr + (4 + wid) * UNIT, scr + (4 + wid) * UNIT + SLOT,
                      scr + (2 * wid + 1) * UNIT, scr + (2 * wid) * UNIT + SLOT, lane);
        __syncthreads();
        if (wid == 0)
            mat16_mul(resB + rd * SLOT, nullptr,
                      scr + 5 * UNIT, scr + 4 * UNIT + SLOT, lane);
    }
    __syncthreads();

    // transposes of the 8 round-results into stage
    for (int e = tid; e < 8 * 256; e += 256) {
        int m = e >> 8, idx = e & 255, j = idx >> 4, r = idx & 15;
        stage[m * SLOT + r * ROWS + j] = resB[m * SLOT + j * ROWS + r];
    }
    __syncthreads();

    // final tree 8 -> 4 -> 2 -> 1
    for (int i = wid; i < 4; i += 4)
        mat16_mul(scr + i * UNIT, scr + i * UNIT + SLOT,
                  resB + (2 * i + 1) * SLOT, stage + (2 * i) * SLOT, lane);
    __syncthreads();
    float* cur = scr;
    float* oth = stage;
    int n = 4;
    while (n > 1) {
        n >>= 1;
        for (int i = wid; i < n; i += 4)
            mat16_mul(oth + i * UNIT, oth + i * UNIT + SLOT,
                      cur + (2 * i + 1) * UNIT, cur + (2 * i) * UNIT + SLOT, lane);
        __syncthreads();
        float* t = cur; cur = oth; oth = t;
    }
    // final combined matrix rows at cur[j*ROWS + k]

    if (tid < 16) {
        int jj = tid;
        float ls = log_sigma[jj];
        float mk = mu[jj];
        float iv = fexp2(-2.0f * LOG2E * ls);
        float A2 = -0.5f * LOG2E * iv;
        float B2 = LOG2E * mk * iv;
        float C2 = LOG2E * (-0.5f * mk * mk * iv - ls - HLOG2PI);
        float x = obvs[(long)bb * NS];                   // t = 0
        float e = fexp2(LOG2E * prior_logits[jj]);
        float Z = gsum16(e);
        float p0 = fexp2(fmaf(x, fmaf(x, A2, B2), C2)) * e;
        const float* Mrow = cur + jj * ROWS;
        float mr[16];
        *(float4*)&mr[0]  = ((const float4*)Mrow)[0];
        *(float4*)&mr[4]  = ((const float4*)Mrow)[1];
        *(float4*)&mr[8]  = ((const float4*)Mrow)[2];
        *(float4*)&mr[12] = ((const float4*)Mrow)[3];
        float q = 0.0f;
#pragma unroll
        for (int rr = 0; rr < 16; ++rr) q = fmaf(mr[rr], __shfl(p0, rr, 16), q);
        float Tq = gsum16(q);
        const float* pm = wsM + bb * NC + jj * 4;
        float msum = gsum16(pm[0] + pm[1] + pm[2] + pm[3]);
        if (jj == 0) {
            float res = (flog2(Tq) - flog2(Z) + msum) * LN2;
            atomicAdd(out, res);
        }
    }
}

extern "C" void kernel_launch(void* const* d_in, const int* in_sizes, int n_in,
                              void* d_out, int out_size, void* d_ws, size_t ws_size,
                              hipStream_t stream) {
    const float* obvs = (const float*)d_in[0];
    const float* mu = (const float*)d_in[1];
    const float* log_sigma = (const float*)d_in[2];
    const float* prior_logits = (const float*)d_in[3];
    float* out = (float*)d_out;

    float* wsW = (float*)d_ws;                          // NB*NC*256 floats = 8.39 MB
    float* wsM = wsW + (size_t)NB * NC * 256;           // 8192 floats

    hmm_phase1<<<dim3(NB * NC * 16 / 256), dim3(256), 0, stream>>>(obvs, mu, log_sigma,
                                                                   wsW, wsM, out);
    hmm_phase23<<<dim3(NB), dim3(256), 0, stream>>>(obvs, mu, log_sigma, prior_logits,
                                                    wsW, wsM, out);
}

// Round 12
// 106.353 us; speedup vs baseline: 1.0564x; 1.0564x over previous
//
#include <hip/hip_runtime.h>

#define NB 128
#define NS 8192
#define NC 128                // phase1 chunks per sequence (64-step chunks)
#define NCP 64                // pair-combined matrices per sequence (phase23 input)
#define NL (NS / NC)          // 64 steps per chunk
#define M4 (NL / 4)           // 16 float4 groups

#define LOG2E 1.4426950408889634f
#define HLOG2PI 0.918938533204672742f
#define LN2 0.69314718055994531f

// LDS matrix layout (round-6/8/9/11-proven)
#define ROWS 20          // padded leading dim
#define UNIT 640         // dual unit: R[16x20] + T[16x20]
#define SLOT 320

__device__ __forceinline__ float fexp2(float x) { return __builtin_amdgcn_exp2f(x); }
__device__ __forceinline__ float flog2(float x) { return __builtin_amdgcn_logf(x); }

__device__ __forceinline__ float gsum16(float v) {
    v += __shfl_xor(v, 1, 16);
    v += __shfl_xor(v, 2, 16);
    v += __shfl_xor(v, 4, 16);
    v += __shfl_xor(v, 8, 16);
    return v;
}
__device__ __forceinline__ float gmax16(float v) {
    v = fmaxf(v, __shfl_xor(v, 1, 16));
    v = fmaxf(v, __shfl_xor(v, 2, 16));
    v = fmaxf(v, __shfl_xor(v, 4, 16));
    v = fmaxf(v, __shfl_xor(v, 8, 16));
    return v;
}

template <int K>
__device__ __forceinline__ int rotk(int x) {
    return __builtin_amdgcn_mov_dpp(x, 0x120 + K, 0xF, 0xF, true);
}

// One HMM step in rotated-W layout (r8/9/11-proven scalar form).
__device__ __forceinline__ float step2(float (&W)[16], float T, float xx,
                                       float A2, float B2, float C2) {
    const float amb = 0.9f - 0.1f / 15.0f;
    const float bco = 0.1f / 15.0f;
    float myl = fexp2(fmaf(xx, fmaf(xx, A2, B2), C2));   // ONE exp per lane
    int mi = __float_as_int(myl);
    float bT = bco * T;
    W[0]  = fmaf(amb, W[0],  bT) * myl;
    W[1]  = fmaf(amb, W[1],  bT) * __int_as_float(rotk<1>(mi));
    W[2]  = fmaf(amb, W[2],  bT) * __int_as_float(rotk<2>(mi));
    W[3]  = fmaf(amb, W[3],  bT) * __int_as_float(rotk<3>(mi));
    W[4]  = fmaf(amb, W[4],  bT) * __int_as_float(rotk<4>(mi));
    W[5]  = fmaf(amb, W[5],  bT) * __int_as_float(rotk<5>(mi));
    W[6]  = fmaf(amb, W[6],  bT) * __int_as_float(rotk<6>(mi));
    W[7]  = fmaf(amb, W[7],  bT) * __int_as_float(rotk<7>(mi));
    W[8]  = fmaf(amb, W[8],  bT) * __int_as_float(rotk<8>(mi));
    W[9]  = fmaf(amb, W[9],  bT) * __int_as_float(rotk<9>(mi));
    W[10] = fmaf(amb, W[10], bT) * __int_as_float(rotk<10>(mi));
    W[11] = fmaf(amb, W[11], bT) * __int_as_float(rotk<11>(mi));
    W[12] = fmaf(amb, W[12], bT) * __int_as_float(rotk<12>(mi));
    W[13] = fmaf(amb, W[13], bT) * __int_as_float(rotk<13>(mi));
    W[14] = fmaf(amb, W[14], bT) * __int_as_float(rotk<14>(mi));
    W[15] = fmaf(amb, W[15], bT) * __int_as_float(rotk<15>(mi));
    float s0 = (W[0] + W[1]) + (W[2] + W[3]);
    float s1 = (W[4] + W[5]) + (W[6] + W[7]);
    float s2 = (W[8] + W[9]) + (W[10] + W[11]);
    float s3 = (W[12] + W[13]) + (W[14] + W[15]);
    return (s0 + s1) + (s2 + s3);
}

// Phase 1 (nc=128 -> 4 waves/SIMD): thread (b, chunk c, column r) evolves basis
// e_r through a 64-step chunk (guarded per-4-step renorm — r8/9/11-proven
// cadence), normalizes to max colsum 1, writes to LDS dual layout; the block
// then pair-combines its 16 chunks into 8 products WITH RENORMALIZATION
// (r10's inf: unnormalized pair products compounded a ~-20-bit/level deficit
// through the phase23 tree into exact-0 colsums). LDS 40,960 B x 4 blocks/CU
// = exactly 160 KiB.
__global__ __launch_bounds__(256, 4) void hmm_phase1(const float* __restrict__ obvs,
                                                     const float* __restrict__ mu,
                                                     const float* __restrict__ log_sigma,
                                                     float* __restrict__ wsW,
                                                     float* __restrict__ wsM,
                                                     float* __restrict__ out) {
    __shared__ float lds[16 * UNIT];       // 16 dual units, 40,960 B
    int tid = blockIdx.x * 256 + threadIdx.x;
    if (tid == 0) out[0] = 0.0f;           // phase23 atomicAdds after this dispatch
    int r = threadIdx.x & 15;
    int u = threadIdx.x >> 4;              // local chunk 0..15
    int g = tid >> 4;                      // g = b*NC + c
    int b = g >> 7;
    int c = g & (NC - 1);

    float ls = log_sigma[r];
    float mk = mu[r];
    float iv = fexp2(-2.0f * LOG2E * ls);
    float A2 = -0.5f * LOG2E * iv;
    float B2 = LOG2E * mk * iv;
    float C2 = LOG2E * (-0.5f * mk * mk * iv - ls - HLOG2PI);

    float W[16];
#pragma unroll
    for (int k = 0; k < 16; ++k) W[k] = (k == 0) ? 1.0f : 0.0f;  // identity, rotated layout
    int ilog = 0;
    float T = 1.0f;

    const float4* ob4 = (const float4*)(obvs + (long)b * NS) + c * M4;
    float4 xv = ob4[0];
    float4 xn = ob4[1];
    // peeled m=0 group: chunk 0 skips t=0 (handled as init vector in phase23)
    if (c) T = step2(W, T, xv.x, A2, B2, C2);
    T = step2(W, T, xv.y, A2, B2, C2);
    T = step2(W, T, xv.z, A2, B2, C2);
    T = step2(W, T, xv.w, A2, B2, C2);
    {
        int te = (__float_as_int(T) >> 23) & 255;
        int ok = (te != 0);
        float s = ok ? __int_as_float((254 - te) << 23) : 1.0f;
        ilog += ok ? (te - 127) : 0;
#pragma unroll
        for (int k = 0; k < 16; ++k) W[k] *= s;
        T *= s;
    }
    xv = xn;
    for (int m = 1; m < M4; ++m) {
        xn = ob4[(m + 1) < M4 ? (m + 1) : m];
        T = step2(W, T, xv.x, A2, B2, C2);
        T = step2(W, T, xv.y, A2, B2, C2);
        T = step2(W, T, xv.z, A2, B2, C2);
        T = step2(W, T, xv.w, A2, B2, C2);
        // guarded branchless exponent renorm (r8/9/11-proven)
        int te = (__float_as_int(T) >> 23) & 255;
        int ok = (te != 0);
        float s = ok ? __int_as_float((254 - te) << 23) : 1.0f;
        ilog += ok ? (te - 127) : 0;
#pragma unroll
        for (int k = 0; k < 16; ++k) W[k] *= s;
        T *= s;
        xv = xn;
    }

    int sid[16];
    sid[0] = r;
    sid[1]  = rotk<1>(r);   sid[2]  = rotk<2>(r);   sid[3]  = rotk<3>(r);
    sid[4]  = rotk<4>(r);   sid[5]  = rotk<5>(r);   sid[6]  = rotk<6>(r);
    sid[7]  = rotk<7>(r);   sid[8]  = rotk<8>(r);   sid[9]  = rotk<9>(r);
    sid[10] = rotk<10>(r);  sid[11] = rotk<11>(r);  sid[12] = rotk<12>(r);
    sid[13] = rotk<13>(r);  sid[14] = rotk<14>(r);  sid[15] = rotk<15>(r);

    float lg = (float)ilog + flog2(T);     // true column log2-sum (T in [1,2))
    float mx = gmax16(lg);                 // chunk max over 16 columns
    float sc = fexp2((float)ilog - mx);    // scale so chunk max colsum = 1

    // write normalized chunk matrix into LDS dual layout; mx in the j=0 pad hole
    float* Ru = lds + u * UNIT;
    float* Tu = lds + u * UNIT + SLOT;
#pragma unroll
    for (int k = 0; k < 16; ++k) {
        float w = W[k] * sc;
        int j = sid[k];
        Ru[j * ROWS + r] = w;
        Tu[r * ROWS + j] = w;
    }
    if (r == 0) Ru[16] = mx;
    __syncthreads();

    // pair-combine WITH renormalization: wave wid does products p=2*wid(+1);
    // P = M_{2p+1} * M_{2p}; rescale so max colsum = 1; store [p][j][r] layout.
    int lane = threadIdx.x & 63;
    int wid = threadIdx.x >> 6;
    long p0 = (long)blockIdx.x * 8;        // = b*NCP + (c0/2)
#pragma unroll
    for (int q = 0; q < 2; ++q) {
        int p = 2 * wid + q;
        const float* MbR = lds + (2 * p + 1) * UNIT;
        const float* MaT = lds + (2 * p) * UNIT + SLOT;
        int a = lane >> 3, cc = lane & 7;
        float b0[16], b1[16], a0[16], a1[16];
        const float4* pb0 = (const float4*)(MbR + (2 * a) * ROWS);
        const float4* pb1 = (const float4*)(MbR + (2 * a + 1) * ROWS);
        const float4* pa0 = (const float4*)(MaT + (2 * cc) * ROWS);
        const float4* pa1 = (const float4*)(MaT + (2 * cc + 1) * ROWS);
#pragma unroll
        for (int qq = 0; qq < 4; ++qq) {
            *(float4*)&b0[4 * qq] = pb0[qq];
            *(float4*)&b1[4 * qq] = pb1[qq];
            *(float4*)&a0[4 * qq] = pa0[qq];
            *(float4*)&a1[4 * qq] = pa1[qq];
        }
        float c00 = 0.f, c01 = 0.f, c10 = 0.f, c11 = 0.f;
#pragma unroll
        for (int k = 0; k < 16; ++k) {
            c00 = fmaf(b0[k], a0[k], c00);
            c01 = fmaf(b0[k], a1[k], c01);
            c10 = fmaf(b1[k], a0[k], c10);
            c11 = fmaf(b1[k], a1[k], c11);
        }
        // product colsums: reduce over row-lanes (a = lane bits 3..5)
        float cs0 = c00 + c10;
        float cs1 = c01 + c11;
        cs0 += __shfl_xor(cs0, 8);  cs1 += __shfl_xor(cs1, 8);
        cs0 += __shfl_xor(cs0, 16); cs1 += __shfl_xor(cs1, 16);
        cs0 += __shfl_xor(cs0, 32); cs1 += __shfl_xor(cs1, 32);
        // max colsum over the 16 columns (cc = lane bits 0..2, 2 cols per lane)
        float mxc = fmaxf(cs0, cs1);
        mxc = fmaxf(mxc, __shfl_xor(mxc, 1));
        mxc = fmaxf(mxc, __shfl_xor(mxc, 2));
        mxc = fmaxf(mxc, __shfl_xor(mxc, 4));
        float is = 1.0f / mxc;                  // mxc > 0: all entries strictly positive
        float* dst = wsW + (p0 + p) * 256;
        *(float2*)(dst + (2 * a) * 16 + 2 * cc)     = make_float2(c00 * is, c01 * is);
        *(float2*)(dst + (2 * a + 1) * 16 + 2 * cc) = make_float2(c10 * is, c11 * is);
        if (lane == 0) {
            float mxa = lds[(2 * p) * UNIT + 16];
            float mxb = lds[(2 * p + 1) * UNIT + 16];
            wsM[p0 + p] = mxa + mxb + flog2(mxc);
        }
    }
}

// P = Mb * Ma, one product per wave (round-6/8/9/11-proven).
__device__ __forceinline__ void mat16_mul(float* dR, float* dT,
                                          const float* MbR, const float* MaT,
                                          int lane) {
    int a = lane >> 3;
    int cc = lane & 7;
    float b0[16], b1[16], a0[16], a1[16];
    const float4* pb0 = (const float4*)(MbR + (2 * a) * ROWS);
    const float4* pb1 = (const float4*)(MbR + (2 * a + 1) * ROWS);
    const float4* pa0 = (const float4*)(MaT + (2 * cc) * ROWS);
    const float4* pa1 = (const float4*)(MaT + (2 * cc + 1) * ROWS);
#pragma unroll
    for (int q = 0; q < 4; ++q) {
        *(float4*)&b0[4 * q] = pb0[q];
        *(float4*)&b1[4 * q] = pb1[q];
        *(float4*)&a0[4 * q] = pa0[q];
        *(float4*)&a1[4 * q] = pa1[q];
    }
    float c00 = 0.f, c01 = 0.f, c10 = 0.f, c11 = 0.f;
#pragma unroll
    for (int k = 0; k < 16; ++k) {
        c00 = fmaf(b0[k], a0[k], c00);
        c01 = fmaf(b0[k], a1[k], c01);
        c10 = fmaf(b1[k], a0[k], c10);
        c11 = fmaf(b1[k], a1[k], c11);
    }
    *(float2*)(dR + (2 * a) * ROWS + 2 * cc)     = make_float2(c00, c01);
    *(float2*)(dR + (2 * a + 1) * ROWS + 2 * cc) = make_float2(c10, c11);
    if (dT) {
        *(float2*)(dT + (2 * cc) * ROWS + 2 * a)     = make_float2(c00, c10);
        *(float2*)(dT + (2 * cc + 1) * ROWS + 2 * a) = make_float2(c01, c11);
    }
}

// Phase 2+3: VERBATIM round-8/9/11-passed kernel (64 matrices per b).
__global__ __launch_bounds__(256, 2) void hmm_phase23(const float* __restrict__ obvs,
                                                      const float* __restrict__ mu,
                                                      const float* __restrict__ log_sigma,
                                                      const float* __restrict__ prior_logits,
                                                      const float* __restrict__ wsW,
                                                      const float* __restrict__ wsM,
                                                      float* __restrict__ out) {
    __shared__ float smem[12800];   // 51,200 B: stage(8x640) + scr(8x640) + resB(8x320)
    float* stage = smem;
    float* scr   = smem + 5120;
    float* resB  = smem + 10240;

    int bb = blockIdx.x;
    int tid = threadIdx.x;
    int wid = tid >> 6;
    int lane = tid & 63;

    for (int rd = 0; rd < 8; ++rd) {
        const float4* src = (const float4*)(wsW + ((long)bb * NCP + rd * 8) * 256);
        __syncthreads();                   // stage reuse vs previous round's reads
#pragma unroll
        for (int q = 0; q < 2; ++q) {
            int f = tid + q * 256;
            float4 v = src[f];
            int m = f >> 6, idx = f & 63, j = idx >> 2, kq = idx & 3;
            *(float4*)(stage + m * UNIT + j * ROWS + kq * 4) = v;
            float* Tb = stage + m * UNIT + SLOT;
            Tb[(4 * kq + 0) * ROWS + j] = v.x;
            Tb[(4 * kq + 1) * ROWS + j] = v.y;
            Tb[(4 * kq + 2) * ROWS + j] = v.z;
            Tb[(4 * kq + 3) * ROWS + j] = v.w;
        }
        __syncthreads();
        // in-round tree 8 -> 4 -> 2 -> 1  (later * earlier)
        if (wid < 4)
            mat16_mul(scr + wid * UNIT, scr + wid * UNIT + SLOT,
                      stage + (2 * wid + 1) * UNIT, stage + (2 * wid) * UNIT + SLOT, lane);
        __syncthreads();
        if (wid < 2)
            mat16_mul(scr + (4 + wid) * UNIT, scr + (4 + wid) * UNIT + SLOT,
                      scr + (2 * wid + 1) * UNIT, scr + (2 * wid) * UNIT + SLOT, lane);
        __syncthreads();
        if (wid == 0)
            mat16_mul(resB + rd * SLOT, nullptr,
                      scr + 5 * UNIT, scr + 4 * UNIT + SLOT, lane);
    }
    __syncthreads();

    // transposes of the 8 round-results into stage
    for (int e = tid; e < 8 * 256; e += 256) {
        int m = e >> 8, idx = e & 255, j = idx >> 4, r = idx & 15;
        stage[m * SLOT + r * ROWS + j] = resB[m * SLOT + j * ROWS + r];
    }
    __syncthreads();

    // final tree 8 -> 4 -> 2 -> 1
    for (int i = wid; i < 4; i += 4)
        mat16_mul(scr + i * UNIT, scr + i * UNIT + SLOT,
                  resB + (2 * i + 1) * SLOT, stage + (2 * i) * SLOT, lane);
    __syncthreads();
    float* cur = scr;
    float* oth = stage;
    int n = 4;
    while (n > 1) {
        n >>= 1;
        for (int i = wid; i < n; i += 4)
            mat16_mul(oth + i * UNIT, oth + i * UNIT + SLOT,
                      cur + (2 * i + 1) * UNIT, cur + (2 * i) * UNIT + SLOT, lane);
        __syncthreads();
        float* t = cur; cur = oth; oth = t;
    }
    // final combined matrix rows at cur[j*ROWS + k]

    if (tid < 16) {
        int jj = tid;
        float ls = log_sigma[jj];
        float mk = mu[jj];
        float iv = fexp2(-2.0f * LOG2E * ls);
        float A2 = -0.5f * LOG2E * iv;
        float B2 = LOG2E * mk * iv;
        float C2 = LOG2E * (-0.5f * mk * mk * iv - ls - HLOG2PI);
        float x = obvs[(long)bb * NS];                   // t = 0
        float e = fexp2(LOG2E * prior_logits[jj]);
        float Z = gsum16(e);
        float p0 = fexp2(fmaf(x, fmaf(x, A2, B2), C2)) * e;
        const float* Mrow = cur + jj * ROWS;
        float mr[16];
        *(float4*)&mr[0]  = ((const float4*)Mrow)[0];
        *(float4*)&mr[4]  = ((const float4*)Mrow)[1];
        *(float4*)&mr[8]  = ((const float4*)Mrow)[2];
        *(float4*)&mr[12] = ((const float4*)Mrow)[3];
        float q = 0.0f;
#pragma unroll
        for (int rr = 0; rr < 16; ++rr) q = fmaf(mr[rr], __shfl(p0, rr, 16), q);
        float Tq = gsum16(q);
        const float* pm = wsM + bb * NCP + jj * 4;
        float msum = gsum16(pm[0] + pm[1] + pm[2] + pm[3]);
        if (jj == 0) {
            float res = (flog2(Tq) - flog2(Z) + msum) * LN2;
            atomicAdd(out, res);
        }
    }
}

extern "C" void kernel_launch(void* const* d_in, const int* in_sizes, int n_in,
                              void* d_out, int out_size, void* d_ws, size_t ws_size,
                              hipStream_t stream) {
    const float* obvs = (const float*)d_in[0];
    const float* mu = (const float*)d_in[1];
    const float* log_sigma = (const float*)d_in[2];
    const float* prior_logits = (const float*)d_in[3];
    float* out = (float*)d_out;

    float* wsW = (float*)d_ws;                          // NB*NCP*256 floats = 8.39 MB
    float* wsM = wsW + (size_t)NB * NCP * 256;          // NB*NCP floats

    hmm_phase1<<<dim3(NB * NC * 16 / 256), dim3(256), 0, stream>>>(obvs, mu, log_sigma,
                                                                   wsW, wsM, out);
    hmm_phase23<<<dim3(NB), dim3(256), 0, stream>>>(obvs, mu, log_sigma, prior_logits,
                                                    wsW, wsM, out);
}

// Round 13
// 96.359 us; speedup vs baseline: 1.1659x; 1.1037x over previous
//
#include <hip/hip_runtime.h>

#define NB 128
#define NS 8192
#define NC 128                // phase1 chunks per sequence (64-step chunks)
#define NCP 8                 // combined matrices per sequence (16 chunks -> 1 per block)
#define NL (NS / NC)          // 64 steps per chunk
#define M4 (NL / 4)           // 16 float4 groups

#define LOG2E 1.4426950408889634f
#define HLOG2PI 0.918938533204672742f
#define LN2 0.69314718055994531f

// LDS matrix layout (r6/8/9/11/12-proven)
#define ROWS 20          // padded leading dim
#define UNIT 640         // dual unit: R[16x20] + T[16x20]
#define SLOT 320

__device__ __forceinline__ float fexp2(float x) { return __builtin_amdgcn_exp2f(x); }
__device__ __forceinline__ float flog2(float x) { return __builtin_amdgcn_logf(x); }

__device__ __forceinline__ float gsum16(float v) {
    v += __shfl_xor(v, 1, 16);
    v += __shfl_xor(v, 2, 16);
    v += __shfl_xor(v, 4, 16);
    v += __shfl_xor(v, 8, 16);
    return v;
}
__device__ __forceinline__ float gmax16(float v) {
    v = fmaxf(v, __shfl_xor(v, 1, 16));
    v = fmaxf(v, __shfl_xor(v, 2, 16));
    v = fmaxf(v, __shfl_xor(v, 4, 16));
    v = fmaxf(v, __shfl_xor(v, 8, 16));
    return v;
}

template <int K>
__device__ __forceinline__ int rotk(int x) {
    return __builtin_amdgcn_mov_dpp(x, 0x120 + K, 0xF, 0xF, true);
}

// One HMM step in rotated-W layout (r8/9/11/12-proven scalar form).
__device__ __forceinline__ float step2(float (&W)[16], float T, float xx,
                                       float A2, float B2, float C2) {
    const float amb = 0.9f - 0.1f / 15.0f;
    const float bco = 0.1f / 15.0f;
    float myl = fexp2(fmaf(xx, fmaf(xx, A2, B2), C2));   // ONE exp per lane
    int mi = __float_as_int(myl);
    float bT = bco * T;
    W[0]  = fmaf(amb, W[0],  bT) * myl;
    W[1]  = fmaf(amb, W[1],  bT) * __int_as_float(rotk<1>(mi));
    W[2]  = fmaf(amb, W[2],  bT) * __int_as_float(rotk<2>(mi));
    W[3]  = fmaf(amb, W[3],  bT) * __int_as_float(rotk<3>(mi));
    W[4]  = fmaf(amb, W[4],  bT) * __int_as_float(rotk<4>(mi));
    W[5]  = fmaf(amb, W[5],  bT) * __int_as_float(rotk<5>(mi));
    W[6]  = fmaf(amb, W[6],  bT) * __int_as_float(rotk<6>(mi));
    W[7]  = fmaf(amb, W[7],  bT) * __int_as_float(rotk<7>(mi));
    W[8]  = fmaf(amb, W[8],  bT) * __int_as_float(rotk<8>(mi));
    W[9]  = fmaf(amb, W[9],  bT) * __int_as_float(rotk<9>(mi));
    W[10] = fmaf(amb, W[10], bT) * __int_as_float(rotk<10>(mi));
    W[11] = fmaf(amb, W[11], bT) * __int_as_float(rotk<11>(mi));
    W[12] = fmaf(amb, W[12], bT) * __int_as_float(rotk<12>(mi));
    W[13] = fmaf(amb, W[13], bT) * __int_as_float(rotk<13>(mi));
    W[14] = fmaf(amb, W[14], bT) * __int_as_float(rotk<14>(mi));
    W[15] = fmaf(amb, W[15], bT) * __int_as_float(rotk<15>(mi));
    float s0 = (W[0] + W[1]) + (W[2] + W[3]);
    float s1 = (W[4] + W[5]) + (W[6] + W[7]);
    float s2 = (W[8] + W[9]) + (W[10] + W[11]);
    float s3 = (W[12] + W[13]) + (W[14] + W[15]);
    return (s0 + s1) + (s2 + s3);
}

// Renormalized product of two LDS dual units: unit[ud] = norm(M[ub] * M[ua]),
// ua = earlier (T layout used), ub = later (R layout used). Result written in
// dual layout to unit ud (= ua: only this wave touches it this level — safe).
// Combined log-scale -> pad hole lds[ud*UNIT+16]. (r12-proven renorm pattern.)
__device__ __forceinline__ void combineUnits(float* lds, int ua, int ub, int ud, int lane) {
    const float* MbR = lds + ub * UNIT;
    const float* MaT = lds + ua * UNIT + SLOT;
    float mxa = lds[ua * UNIT + 16];
    float mxb = lds[ub * UNIT + 16];
    int a = lane >> 3, cc = lane & 7;
    float b0[16], b1[16], a0[16], a1[16];
    const float4* pb0 = (const float4*)(MbR + (2 * a) * ROWS);
    const float4* pb1 = (const float4*)(MbR + (2 * a + 1) * ROWS);
    const float4* pa0 = (const float4*)(MaT + (2 * cc) * ROWS);
    const float4* pa1 = (const float4*)(MaT + (2 * cc + 1) * ROWS);
#pragma unroll
    for (int q = 0; q < 4; ++q) {
        *(float4*)&b0[4 * q] = pb0[q];
        *(float4*)&b1[4 * q] = pb1[q];
        *(float4*)&a0[4 * q] = pa0[q];
        *(float4*)&a1[4 * q] = pa1[q];
    }
    float c00 = 0.f, c01 = 0.f, c10 = 0.f, c11 = 0.f;
#pragma unroll
    for (int k = 0; k < 16; ++k) {
        c00 = fmaf(b0[k], a0[k], c00);
        c01 = fmaf(b0[k], a1[k], c01);
        c10 = fmaf(b1[k], a0[k], c10);
        c11 = fmaf(b1[k], a1[k], c11);
    }
    // colsums over row-lanes (lane bits 3..5), then max over column-lanes (0..2)
    float cs0 = c00 + c10;
    float cs1 = c01 + c11;
    cs0 += __shfl_xor(cs0, 8);  cs1 += __shfl_xor(cs1, 8);
    cs0 += __shfl_xor(cs0, 16); cs1 += __shfl_xor(cs1, 16);
    cs0 += __shfl_xor(cs0, 32); cs1 += __shfl_xor(cs1, 32);
    float mxc = fmaxf(cs0, cs1);
    mxc = fmaxf(mxc, __shfl_xor(mxc, 1));
    mxc = fmaxf(mxc, __shfl_xor(mxc, 2));
    mxc = fmaxf(mxc, __shfl_xor(mxc, 4));
    float is = 1.0f / mxc;                  // entries strictly positive -> mxc > 0
    c00 *= is; c01 *= is; c10 *= is; c11 *= is;
    float* dR = lds + ud * UNIT;
    float* dT = lds + ud * UNIT + SLOT;
    *(float2*)(dR + (2 * a) * ROWS + 2 * cc)     = make_float2(c00, c01);
    *(float2*)(dR + (2 * a + 1) * ROWS + 2 * cc) = make_float2(c10, c11);
    *(float2*)(dT + (2 * cc) * ROWS + 2 * a)     = make_float2(c00, c10);
    *(float2*)(dT + (2 * cc + 1) * ROWS + 2 * a) = make_float2(c01, c11);
    if (lane == 0) lds[ud * UNIT + 16] = mxa + mxb + flog2(mxc);
}

// Phase 1 (nc=128, 4 waves/SIMD): thread (b, chunk c, column r) evolves basis
// e_r through a 64-step chunk (guarded per-4-step renorm), writes the
// normalized chunk matrix to LDS, then the block tree-combines its 16 chunks
// 16->8->4->2->1 WITH per-level renormalization (INVARIANT: every stored or
// combined matrix is max-colsum-normalized — violations caused r5/r7/r10 infs).
// Emits ONE matrix + scale per block (8 per b). LDS 40,960 B = 4 blocks/CU.
__global__ __launch_bounds__(256, 4) void hmm_phase1(const float* __restrict__ obvs,
                                                     const float* __restrict__ mu,
                                                     const float* __restrict__ log_sigma,
                                                     float* __restrict__ wsW,
                                                     float* __restrict__ wsM,
                                                     float* __restrict__ out) {
    __shared__ float lds[16 * UNIT];       // 16 dual units, 40,960 B
    int tid = blockIdx.x * 256 + threadIdx.x;
    if (tid == 0) out[0] = 0.0f;           // phase23 atomicAdds after this dispatch
    int r = threadIdx.x & 15;
    int u = threadIdx.x >> 4;              // local chunk 0..15
    int g = tid >> 4;                      // g = b*NC + c
    int b = g >> 7;
    int c = g & (NC - 1);

    float ls = log_sigma[r];
    float mk = mu[r];
    float iv = fexp2(-2.0f * LOG2E * ls);
    float A2 = -0.5f * LOG2E * iv;
    float B2 = LOG2E * mk * iv;
    float C2 = LOG2E * (-0.5f * mk * mk * iv - ls - HLOG2PI);

    float W[16];
#pragma unroll
    for (int k = 0; k < 16; ++k) W[k] = (k == 0) ? 1.0f : 0.0f;  // identity, rotated layout
    int ilog = 0;
    float T = 1.0f;

    const float4* ob4 = (const float4*)(obvs + (long)b * NS) + c * M4;
    float4 xv = ob4[0];
    float4 xn = ob4[1];
    // peeled m=0 group: chunk 0 skips t=0 (handled as init vector in phase23)
    if (c) T = step2(W, T, xv.x, A2, B2, C2);
    T = step2(W, T, xv.y, A2, B2, C2);
    T = step2(W, T, xv.z, A2, B2, C2);
    T = step2(W, T, xv.w, A2, B2, C2);
    {
        int te = (__float_as_int(T) >> 23) & 255;
        int ok = (te != 0);
        float s = ok ? __int_as_float((254 - te) << 23) : 1.0f;
        ilog += ok ? (te - 127) : 0;
#pragma unroll
        for (int k = 0; k < 16; ++k) W[k] *= s;
        T *= s;
    }
    xv = xn;
    for (int m = 1; m < M4; ++m) {
        xn = ob4[(m + 1) < M4 ? (m + 1) : m];
        T = step2(W, T, xv.x, A2, B2, C2);
        T = step2(W, T, xv.y, A2, B2, C2);
        T = step2(W, T, xv.z, A2, B2, C2);
        T = step2(W, T, xv.w, A2, B2, C2);
        // guarded branchless exponent renorm (r8/9/11/12-proven)
        int te = (__float_as_int(T) >> 23) & 255;
        int ok = (te != 0);
        float s = ok ? __int_as_float((254 - te) << 23) : 1.0f;
        ilog += ok ? (te - 127) : 0;
#pragma unroll
        for (int k = 0; k < 16; ++k) W[k] *= s;
        T *= s;
        xv = xn;
    }

    int sid[16];
    sid[0] = r;
    sid[1]  = rotk<1>(r);   sid[2]  = rotk<2>(r);   sid[3]  = rotk<3>(r);
    sid[4]  = rotk<4>(r);   sid[5]  = rotk<5>(r);   sid[6]  = rotk<6>(r);
    sid[7]  = rotk<7>(r);   sid[8]  = rotk<8>(r);   sid[9]  = rotk<9>(r);
    sid[10] = rotk<10>(r);  sid[11] = rotk<11>(r);  sid[12] = rotk<12>(r);
    sid[13] = rotk<13>(r);  sid[14] = rotk<14>(r);  sid[15] = rotk<15>(r);

    float lg = (float)ilog + flog2(T);     // true column log2-sum (T in [1,2))
    float mx = gmax16(lg);                 // chunk max over 16 columns
    float sc = fexp2((float)ilog - mx);    // scale so chunk max colsum = 1

    // normalized chunk matrix into LDS dual layout; mx in the j=0 pad hole
    float* Ru = lds + u * UNIT;
    float* Tu = lds + u * UNIT + SLOT;
#pragma unroll
    for (int k = 0; k < 16; ++k) {
        float w = W[k] * sc;
        int j = sid[k];
        Ru[j * ROWS + r] = w;
        Tu[r * ROWS + j] = w;
    }
    if (r == 0) Ru[16] = mx;
    __syncthreads();

    // in-LDS tree 16 -> 8 -> 4 -> 2 -> 1, renormalized each level.
    // Result of product p written to its EARLIER source unit (no cross-wave hazard).
    int lane = threadIdx.x & 63;
    int wid = threadIdx.x >> 6;
    // level 1: 8 products; wave wid does p = 2*wid, 2*wid+1
#pragma unroll
    for (int q = 0; q < 2; ++q) {
        int p = 2 * wid + q;
        combineUnits(lds, 2 * p, 2 * p + 1, 2 * p, lane);
    }
    __syncthreads();
    // level 2: 4 products; sources at stride 2
    if (wid < 4) combineUnits(lds, 4 * wid, 4 * wid + 2, 4 * wid, lane);
    __syncthreads();
    // level 3: 2 products; stride 4
    if (wid < 2) combineUnits(lds, 8 * wid, 8 * wid + 4, 8 * wid, lane);
    __syncthreads();
    // level 4: 1 product; stride 8
    if (wid == 0) combineUnits(lds, 0, 8, 0, lane);
    __syncthreads();

    // emit: one matrix per block in [j][r] layout + its log2-scale
    wsW[(long)blockIdx.x * 256 + threadIdx.x] =
        lds[(threadIdx.x >> 4) * ROWS + (threadIdx.x & 15)];
    if (threadIdx.x == 0) wsM[blockIdx.x] = lds[16];
}

// P = Mb * Ma, one product per wave (r6/8/9/11/12-proven).
__device__ __forceinline__ void mat16_mul(float* dR, float* dT,
                                          const float* MbR, const float* MaT,
                                          int lane) {
    int a = lane >> 3;
    int cc = lane & 7;
    float b0[16], b1[16], a0[16], a1[16];
    const float4* pb0 = (const float4*)(MbR + (2 * a) * ROWS);
    const float4* pb1 = (const float4*)(MbR + (2 * a + 1) * ROWS);
    const float4* pa0 = (const float4*)(MaT + (2 * cc) * ROWS);
    const float4* pa1 = (const float4*)(MaT + (2 * cc + 1) * ROWS);
#pragma unroll
    for (int q = 0; q < 4; ++q) {
        *(float4*)&b0[4 * q] = pb0[q];
        *(float4*)&b1[4 * q] = pb1[q];
        *(float4*)&a0[4 * q] = pa0[q];
        *(float4*)&a1[4 * q] = pa1[q];
    }
    float c00 = 0.f, c01 = 0.f, c10 = 0.f, c11 = 0.f;
#pragma unroll
    for (int k = 0; k < 16; ++k) {
        c00 = fmaf(b0[k], a0[k], c00);
        c01 = fmaf(b0[k], a1[k], c01);
        c10 = fmaf(b1[k], a0[k], c10);
        c11 = fmaf(b1[k], a1[k], c11);
    }
    *(float2*)(dR + (2 * a) * ROWS + 2 * cc)     = make_float2(c00, c01);
    *(float2*)(dR + (2 * a + 1) * ROWS + 2 * cc) = make_float2(c10, c11);
    if (dT) {
        *(float2*)(dT + (2 * cc) * ROWS + 2 * a)     = make_float2(c00, c10);
        *(float2*)(dT + (2 * cc + 1) * ROWS + 2 * a) = make_float2(c01, c11);
    }
}

// Phase 2+3: one block per b, EIGHT input matrices (r12's staging + in-round
// tree code verbatim, single round), then the r12 epilogue.
__global__ __launch_bounds__(256, 2) void hmm_phase23(const float* __restrict__ obvs,
                                                      const float* __restrict__ mu,
                                                      const float* __restrict__ log_sigma,
                                                      const float* __restrict__ prior_logits,
                                                      const float* __restrict__ wsW,
                                                      const float* __restrict__ wsM,
                                                      float* __restrict__ out) {
    __shared__ float smem[10560];   // stage(8x640) + scr(8x640) + resB(320)
    float* stage = smem;
    float* scr   = smem + 5120;
    float* resB  = smem + 10240;

    int bb = blockIdx.x;
    int tid = threadIdx.x;
    int wid = tid >> 6;
    int lane = tid & 63;

    // stage 8 matrices in dual layout (r12's staging code, one round)
    const float4* src = (const float4*)(wsW + (long)bb * NCP * 256);
#pragma unroll
    for (int q = 0; q < 2; ++q) {
        int f = tid + q * 256;
        float4 v = src[f];
        int m = f >> 6, idx = f & 63, j = idx >> 2, kq = idx & 3;
        *(float4*)(stage + m * UNIT + j * ROWS + kq * 4) = v;
        float* Tb = stage + m * UNIT + SLOT;
        Tb[(4 * kq + 0) * ROWS + j] = v.x;
        Tb[(4 * kq + 1) * ROWS + j] = v.y;
        Tb[(4 * kq + 2) * ROWS + j] = v.z;
        Tb[(4 * kq + 3) * ROWS + j] = v.w;
    }
    __syncthreads();
    // tree 8 -> 4 -> 2 -> 1  (later * earlier)
    if (wid < 4)
        mat16_mul(scr + wid * UNIT, scr + wid * UNIT + SLOT,
                  stage + (2 * wid + 1) * UNIT, stage + (2 * wid) * UNIT + SLOT, lane);
    __syncthreads();
    if (wid < 2)
        mat16_mul(scr + (4 + wid) * UNIT, scr + (4 + wid) * UNIT + SLOT,
                  scr + (2 * wid + 1) * UNIT, scr + (2 * wid) * UNIT + SLOT, lane);
    __syncthreads();
    if (wid == 0)
        mat16_mul(resB, nullptr, scr + 5 * UNIT, scr + 4 * UNIT + SLOT, lane);
    __syncthreads();
    // final combined matrix rows at resB[j*ROWS + k]

    if (tid < 16) {
        int jj = tid;
        float ls = log_sigma[jj];
        float mk = mu[jj];
        float iv = fexp2(-2.0f * LOG2E * ls);
        float A2 = -0.5f * LOG2E * iv;
        float B2 = LOG2E * mk * iv;
        float C2 = LOG2E * (-0.5f * mk * mk * iv - ls - HLOG2PI);
        float x = obvs[(long)bb * NS];                   // t = 0
        float e = fexp2(LOG2E * prior_logits[jj]);
        float Z = gsum16(e);
        float p0 = fexp2(fmaf(x, fmaf(x, A2, B2), C2)) * e;
        const float* Mrow = resB + jj * ROWS;
        float mr[16];
        *(float4*)&mr[0]  = ((const float4*)Mrow)[0];
        *(float4*)&mr[4]  = ((const float4*)Mrow)[1];
        *(float4*)&mr[8]  = ((const float4*)Mrow)[2];
        *(float4*)&mr[12] = ((const float4*)Mrow)[3];
        float q = 0.0f;
#pragma unroll
        for (int rr = 0; rr < 16; ++rr) q = fmaf(mr[rr], __shfl(p0, rr, 16), q);
        float Tq = gsum16(q);
        float pm = (jj < NCP) ? wsM[bb * NCP + jj] : 0.0f;
        float msum = gsum16(pm);
        if (jj == 0) {
            float res = (flog2(Tq) - flog2(Z) + msum) * LN2;
            atomicAdd(out, res);
        }
    }
}

extern "C" void kernel_launch(void* const* d_in, const int* in_sizes, int n_in,
                              void* d_out, int out_size, void* d_ws, size_t ws_size,
                              hipStream_t stream) {
    const float* obvs = (const float*)d_in[0];
    const float* mu = (const float*)d_in[1];
    const float* log_sigma = (const float*)d_in[2];
    const float* prior_logits = (const float*)d_in[3];
    float* out = (float*)d_out;

    float* wsW = (float*)d_ws;                          // NB*NCP*256 floats = 1.05 MB
    float* wsM = wsW + (size_t)NB * NCP * 256;          // NB*NCP floats

    hmm_phase1<<<dim3(NB * NC * 16 / 256), dim3(256), 0, stream>>>(obvs, mu, log_sigma,
                                                                   wsW, wsM, out);
    hmm_phase23<<<dim3(NB), dim3(256), 0, stream>>>(obvs, mu, log_sigma, prior_logits,
                                                    wsW, wsM, out);
}